// Round 1
// baseline (8398.654 us; speedup 1.0000x reference)
//
#include <hip/hip_runtime.h>
#include <math.h>

#define B_  8
#define S_  512
#define H_  768
#define NH_ 12
#define D_  64
#define I_  3072
#define NTOK (B_*S_)   // 4096

__device__ __forceinline__ float gelu_exact(float x) {
    return 0.5f * x * (1.0f + erff(x * 0.70710678118654752440f));
}

// -------------------- embeddings + LayerNorm --------------------
__global__ void embed_ln_kernel(const int* __restrict__ ids,
                                const float* __restrict__ Wword,
                                const float* __restrict__ Wpos,
                                const float* __restrict__ Wtype,
                                const float* __restrict__ g,
                                const float* __restrict__ b,
                                float* __restrict__ out) {
    int t = blockIdx.x;            // token 0..4095
    int s = t % S_;
    long id = ids[t];
    int tid = threadIdx.x;
    float vals[3];
    float sum = 0.f, sq = 0.f;
    #pragma unroll
    for (int i = 0; i < 3; ++i) {
        int c = tid + 256 * i;
        float e = Wword[id * H_ + c] + Wpos[(long)s * H_ + c] + Wtype[c];
        vals[i] = e; sum += e; sq += e * e;
    }
    __shared__ float r1[256], r2[256];
    r1[tid] = sum; r2[tid] = sq; __syncthreads();
    for (int st = 128; st > 0; st >>= 1) {
        if (tid < st) { r1[tid] += r1[tid + st]; r2[tid] += r2[tid + st]; }
        __syncthreads();
    }
    float mean = r1[0] * (1.0f / H_);
    float var  = r2[0] * (1.0f / H_) - mean * mean;
    float inv  = rsqrtf(var + 1e-12f);
    #pragma unroll
    for (int i = 0; i < 3; ++i) {
        int c = tid + 256 * i;
        out[(long)t * H_ + c] = (vals[i] - mean) * inv * g[c] + b[c];
    }
}

// -------------------- LN(a + r) --------------------
__global__ void add_ln_kernel(const float* __restrict__ a,
                              const float* __restrict__ r,
                              const float* __restrict__ g,
                              const float* __restrict__ bb,
                              float* __restrict__ out) {
    int t = blockIdx.x;
    int tid = threadIdx.x;
    float vals[3];
    float sum = 0.f, sq = 0.f;
    #pragma unroll
    for (int i = 0; i < 3; ++i) {
        int c = tid + 256 * i;
        float e = a[(long)t * H_ + c] + r[(long)t * H_ + c];
        vals[i] = e; sum += e; sq += e * e;
    }
    __shared__ float r1[256], r2[256];
    r1[tid] = sum; r2[tid] = sq; __syncthreads();
    for (int st = 128; st > 0; st >>= 1) {
        if (tid < st) { r1[tid] += r1[tid + st]; r2[tid] += r2[tid + st]; }
        __syncthreads();
    }
    float mean = r1[0] * (1.0f / H_);
    float var  = r2[0] * (1.0f / H_) - mean * mean;
    float inv  = rsqrtf(var + 1e-12f);
    #pragma unroll
    for (int i = 0; i < 3; ++i) {
        int c = tid + 256 * i;
        out[(long)t * H_ + c] = (vals[i] - mean) * inv * g[c] + bb[c];
    }
}

// -------------------- generic NN GEMM: C[M,N] = A[M,K(lda)] * B[K,N] + bias --------------------
// block 256 threads = 16x16, 64x64 tile, 4x4 per thread, K-step 16.
template<int ACT>   // 0 = none, 1 = exact gelu
__global__ void gemm_bias_kernel(const float* __restrict__ A, int lda,
                                 const float* __restrict__ Bm,
                                 const float* __restrict__ bias,
                                 float* __restrict__ C,
                                 int M, int N, int K) {
    __shared__ float As[64][17];
    __shared__ float Bs[16][65];
    int tid = threadIdx.x;
    int tx = tid & 15, ty = tid >> 4;
    int m0 = blockIdx.y * 64, n0 = blockIdx.x * 64;
    int br = tid >> 6, bc = tid & 63;
    float acc[4][4] = {};
    for (int k0 = 0; k0 < K; k0 += 16) {
        #pragma unroll
        for (int i = 0; i < 4; ++i) {
            int r = m0 + ty + 16 * i;
            As[ty + 16 * i][tx] = (r < M) ? A[(long)r * lda + k0 + tx] : 0.f;
        }
        #pragma unroll
        for (int i = 0; i < 4; ++i) {
            Bs[br + 4 * i][bc] = Bm[(long)(k0 + br + 4 * i) * N + n0 + bc];
        }
        __syncthreads();
        #pragma unroll
        for (int kk = 0; kk < 16; ++kk) {
            float a[4], bv[4];
            #pragma unroll
            for (int i = 0; i < 4; ++i) a[i] = As[ty + 16 * i][kk];
            #pragma unroll
            for (int j = 0; j < 4; ++j) bv[j] = Bs[kk][tx + 16 * j];
            #pragma unroll
            for (int i = 0; i < 4; ++i)
                #pragma unroll
                for (int j = 0; j < 4; ++j) acc[i][j] += a[i] * bv[j];
        }
        __syncthreads();
    }
    #pragma unroll
    for (int i = 0; i < 4; ++i) {
        int row = m0 + ty + 16 * i;
        if (row >= M) continue;
        #pragma unroll
        for (int j = 0; j < 4; ++j) {
            int col = n0 + tx + 16 * j;
            float v = acc[i][j] + bias[col];
            if (ACT == 1) v = gelu_exact(v);
            C[(long)row * N + col] = v;
        }
    }
}

// -------------------- scores[bh,i,j] = scale * sum_d Q[b,i,hd,d] K[b,j,hd,d] --------------------
// q,k in (B,S,H) layout; per (b,hd) rows have stride H.
__global__ void attn_scores_kernel(const float* __restrict__ q,
                                   const float* __restrict__ k,
                                   float* __restrict__ scores,
                                   float scale) {
    int bh = blockIdx.z;
    int b = bh / NH_, hd = bh % NH_;
    long base  = (long)b * S_ * H_ + hd * D_;
    long sbase = (long)bh * S_ * S_;
    int q0 = blockIdx.y * 64, k0 = blockIdx.x * 64;
    __shared__ float Qs[64][65], Ks[64][65];
    int tid = threadIdx.x;
    int lr = tid >> 6, lc = tid & 63;
    #pragma unroll
    for (int i = 0; i < 16; ++i) {
        int r = lr + 4 * i;
        Qs[r][lc] = q[base + (long)(q0 + r) * H_ + lc];
        Ks[r][lc] = k[base + (long)(k0 + r) * H_ + lc];
    }
    __syncthreads();
    int tx = tid & 15, ty = tid >> 4;
    float acc[4][4] = {};
    #pragma unroll 4
    for (int kk = 0; kk < 64; ++kk) {
        float a[4], bv[4];
        #pragma unroll
        for (int i = 0; i < 4; ++i) a[i] = Qs[ty + 16 * i][kk];
        #pragma unroll
        for (int j = 0; j < 4; ++j) bv[j] = Ks[tx + 16 * j][kk];
        #pragma unroll
        for (int i = 0; i < 4; ++i)
            #pragma unroll
            for (int j = 0; j < 4; ++j) acc[i][j] += a[i] * bv[j];
    }
    #pragma unroll
    for (int i = 0; i < 4; ++i)
        #pragma unroll
        for (int j = 0; j < 4; ++j)
            scores[sbase + (long)(q0 + ty + 16 * i) * S_ + k0 + tx + 16 * j] = acc[i][j] * scale;
}

// -------------------- row softmax over 512, one wave per row --------------------
__global__ void softmax_kernel(float* __restrict__ scores) {
    long row = blockIdx.x;
    int lane = threadIdx.x;   // 64
    float* p = scores + row * S_;
    float x[8];
    float mx = -1e30f;
    #pragma unroll
    for (int i = 0; i < 8; ++i) { x[i] = p[lane + 64 * i]; mx = fmaxf(mx, x[i]); }
    #pragma unroll
    for (int o = 32; o > 0; o >>= 1) mx = fmaxf(mx, __shfl_xor(mx, o));
    float sum = 0.f;
    #pragma unroll
    for (int i = 0; i < 8; ++i) { x[i] = expf(x[i] - mx); sum += x[i]; }
    #pragma unroll
    for (int o = 32; o > 0; o >>= 1) sum += __shfl_xor(sum, o);
    float inv = 1.f / sum;
    #pragma unroll
    for (int i = 0; i < 8; ++i) p[lane + 64 * i] = x[i] * inv;
}

// -------------------- ctx[b,i,hd,:] = P[bh] @ V[b,:,hd,:] --------------------
__global__ void attn_ctx_kernel(const float* __restrict__ probs,
                                const float* __restrict__ v,
                                float* __restrict__ ctx) {
    int bh = blockIdx.z;
    int b = bh / NH_, hd = bh % NH_;
    long vbase = (long)b * S_ * H_ + hd * D_;
    long sbase = (long)bh * S_ * S_;
    int q0 = blockIdx.y * 64;
    __shared__ float Ps[64][17], Vs[16][65];
    int tid = threadIdx.x;
    int tx = tid & 15, ty = tid >> 4;
    int br = tid >> 6, bc = tid & 63;
    float acc[4][4] = {};
    for (int k0 = 0; k0 < S_; k0 += 16) {
        #pragma unroll
        for (int i = 0; i < 4; ++i)
            Ps[ty + 16 * i][tx] = probs[sbase + (long)(q0 + ty + 16 * i) * S_ + k0 + tx];
        #pragma unroll
        for (int i = 0; i < 4; ++i)
            Vs[br + 4 * i][bc] = v[vbase + (long)(k0 + br + 4 * i) * H_ + bc];
        __syncthreads();
        #pragma unroll
        for (int kk = 0; kk < 16; ++kk) {
            float a[4], bv[4];
            #pragma unroll
            for (int i = 0; i < 4; ++i) a[i] = Ps[ty + 16 * i][kk];
            #pragma unroll
            for (int j = 0; j < 4; ++j) bv[j] = Vs[kk][tx + 16 * j];
            #pragma unroll
            for (int i = 0; i < 4; ++i)
                #pragma unroll
                for (int j = 0; j < 4; ++j) acc[i][j] += a[i] * bv[j];
        }
        __syncthreads();
    }
    #pragma unroll
    for (int i = 0; i < 4; ++i)
        #pragma unroll
        for (int j = 0; j < 4; ++j)
            ctx[(long)b * S_ * H_ + (long)(q0 + ty + 16 * i) * H_ + hd * D_ + tx + 16 * j] = acc[i][j];
}

extern "C" void kernel_launch(void* const* d_in, const int* in_sizes, int n_in,
                              void* d_out, int out_size, void* d_ws, size_t ws_size,
                              hipStream_t stream) {
    const int*   x      = (const int*)  d_in[0];
    const float* W_word = (const float*)d_in[1];
    const float* W_pos  = (const float*)d_in[2];
    const float* W_type = (const float*)d_in[3];
    const float* g_emb  = (const float*)d_in[4];
    const float* b_emb  = (const float*)d_in[5];
    const float* Wq     = (const float*)d_in[6];
    const float* bq     = (const float*)d_in[7];
    const float* Wk     = (const float*)d_in[8];
    const float* bk     = (const float*)d_in[9];
    const float* Wv     = (const float*)d_in[10];
    const float* bv     = (const float*)d_in[11];
    const float* Wo     = (const float*)d_in[12];
    const float* bo     = (const float*)d_in[13];
    const float* g_attn = (const float*)d_in[14];
    const float* b_attn = (const float*)d_in[15];
    const float* Wi     = (const float*)d_in[16];
    const float* bi     = (const float*)d_in[17];
    const float* Wd     = (const float*)d_in[18];
    const float* bd     = (const float*)d_in[19];
    const float* g_out  = (const float*)d_in[20];
    const float* b_out  = (const float*)d_in[21];
    const float* Wp     = (const float*)d_in[22];
    const float* bp     = (const float*)d_in[23];

    const size_t NT = (size_t)NTOK * H_;   // 3,145,728 floats
    float* ws   = (float*)d_ws;
    float* h    = ws;              // (B,S,H)
    float* xa   = h   + NT;        // (B,S,H)
    float* qb   = xa  + NT;        // q proj; reused as ctx
    float* kb   = qb  + NT;        // k proj; reused as proj-out tmp
    float* vb   = kb  + NT;        // v proj
    float* big  = vb  + NT;        // scores (B*NH*S*S = 25,165,824 f) / ff1 out (12.6M f)
    // total ws use: 5*NT + 25,165,824 floats = ~163.6 MB

    embed_ln_kernel<<<NTOK, 256, 0, stream>>>(x, W_word, W_pos, W_type, g_emb, b_emb, h);

    const float scale = 0.125f;   // 1/sqrt(64)
    dim3 g768(12, 64);            // N=768, M=4096
    dim3 g3072(48, 64);           // N=3072
    for (int layer = 0; layer < 6; ++layer) {
        gemm_bias_kernel<0><<<g768, 256, 0, stream>>>(h, H_, Wq, bq, qb, NTOK, H_, H_);
        gemm_bias_kernel<0><<<g768, 256, 0, stream>>>(h, H_, Wk, bk, kb, NTOK, H_, H_);
        gemm_bias_kernel<0><<<g768, 256, 0, stream>>>(h, H_, Wv, bv, vb, NTOK, H_, H_);
        attn_scores_kernel<<<dim3(8, 8, B_ * NH_), 256, 0, stream>>>(qb, kb, big, scale);
        softmax_kernel<<<dim3(B_ * NH_ * S_), 64, 0, stream>>>(big);
        attn_ctx_kernel<<<dim3(1, 8, B_ * NH_), 256, 0, stream>>>(big, vb, qb);  // ctx -> qb
        gemm_bias_kernel<0><<<g768, 256, 0, stream>>>(qb, H_, Wo, bo, kb, NTOK, H_, H_); // -> kb
        add_ln_kernel<<<NTOK, 256, 0, stream>>>(h, kb, g_attn, b_attn, xa);
        gemm_bias_kernel<1><<<g3072, 256, 0, stream>>>(xa, H_, Wi, bi, big, NTOK, I_, H_); // gelu
        gemm_bias_kernel<0><<<g768, 256, 0, stream>>>(big, I_, Wd, bd, kb, NTOK, H_, I_);
        add_ln_kernel<<<NTOK, 256, 0, stream>>>(xa, kb, g_out, b_out, h);
    }

    hipMemcpyAsync(d_out, h, NT * sizeof(float), hipMemcpyDeviceToDevice, stream);
    // pooled = h[:,0,:] @ Wp + bp  (A rows stride S*H)
    gemm_bias_kernel<0><<<dim3(12, 1), 256, 0, stream>>>(h, S_ * H_, Wp, bp,
                                                         (float*)d_out + NT, B_, H_, H_);
}

// Round 2
// 2207.837 us; speedup vs baseline: 3.8040x; 3.8040x over previous
//
#include <hip/hip_runtime.h>
#include <hip/hip_bf16.h>
#include <math.h>

#define B_  8
#define S_  512
#define H_  768
#define NH_ 12
#define D_  64
#define I_  3072
#define NTOK (B_*S_)   // 4096

typedef __attribute__((ext_vector_type(8))) __bf16 bf16x8;
typedef __attribute__((ext_vector_type(4))) float  f32x4;

__device__ __forceinline__ float gelu_exact(float x) {
    return 0.5f * x * (1.0f + erff(x * 0.70710678118654752440f));
}

__device__ __forceinline__ void gload16(const void* g, void* l) {
    __builtin_amdgcn_global_load_lds(
        (const __attribute__((address_space(1))) void*)g,
        (__attribute__((address_space(3))) void*)l,
        16, 0, 0);
}

// -------------------- f32 [K][N] -> bf16 [N][K] transpose-convert --------------------
__global__ void cvtT_kernel(const float* __restrict__ W, __hip_bfloat16* __restrict__ WT,
                            int K, int N) {
    __shared__ float tile[32][33];
    int k0 = blockIdx.y * 32, n0 = blockIdx.x * 32;
    int tx = threadIdx.x & 31, ty = threadIdx.x >> 5;   // 32x8
    #pragma unroll
    for (int i = 0; i < 32; i += 8)
        tile[ty + i][tx] = W[(long)(k0 + ty + i) * N + n0 + tx];
    __syncthreads();
    #pragma unroll
    for (int i = 0; i < 32; i += 8)
        WT[(long)(n0 + ty + i) * K + k0 + tx] = __float2bfloat16(tile[tx][ty + i]);
}

// -------------------- embeddings + LayerNorm (f32 + bf16 outputs) --------------------
__global__ void embed_ln_kernel(const int* __restrict__ ids,
                                const float* __restrict__ Wword,
                                const float* __restrict__ Wpos,
                                const float* __restrict__ Wtype,
                                const float* __restrict__ g,
                                const float* __restrict__ b,
                                float* __restrict__ out,
                                __hip_bfloat16* __restrict__ outb) {
    int t = blockIdx.x;
    int s = t % S_;
    long id = ids[t];
    int tid = threadIdx.x;
    float vals[3];
    float sum = 0.f, sq = 0.f;
    #pragma unroll
    for (int i = 0; i < 3; ++i) {
        int c = tid + 256 * i;
        float e = Wword[id * H_ + c] + Wpos[(long)s * H_ + c] + Wtype[c];
        vals[i] = e; sum += e; sq += e * e;
    }
    __shared__ float r1[256], r2[256];
    r1[tid] = sum; r2[tid] = sq; __syncthreads();
    for (int st = 128; st > 0; st >>= 1) {
        if (tid < st) { r1[tid] += r1[tid + st]; r2[tid] += r2[tid + st]; }
        __syncthreads();
    }
    float mean = r1[0] * (1.0f / H_);
    float var  = r2[0] * (1.0f / H_) - mean * mean;
    float inv  = rsqrtf(var + 1e-12f);
    #pragma unroll
    for (int i = 0; i < 3; ++i) {
        int c = tid + 256 * i;
        float v = (vals[i] - mean) * inv * g[c] + b[c];
        out[(long)t * H_ + c] = v;
        outb[(long)t * H_ + c] = __float2bfloat16(v);
    }
}

// -------------------- LN(a + r) (f32 + bf16 outputs) --------------------
__global__ void add_ln_kernel(const float* __restrict__ a,
                              const float* __restrict__ r,
                              const float* __restrict__ g,
                              const float* __restrict__ bb,
                              float* __restrict__ out,
                              __hip_bfloat16* __restrict__ outb) {
    int t = blockIdx.x;
    int tid = threadIdx.x;
    float vals[3];
    float sum = 0.f, sq = 0.f;
    #pragma unroll
    for (int i = 0; i < 3; ++i) {
        int c = tid + 256 * i;
        float e = a[(long)t * H_ + c] + r[(long)t * H_ + c];
        vals[i] = e; sum += e; sq += e * e;
    }
    __shared__ float r1[256], r2[256];
    r1[tid] = sum; r2[tid] = sq; __syncthreads();
    for (int st = 128; st > 0; st >>= 1) {
        if (tid < st) { r1[tid] += r1[tid + st]; r2[tid] += r2[tid + st]; }
        __syncthreads();
    }
    float mean = r1[0] * (1.0f / H_);
    float var  = r2[0] * (1.0f / H_) - mean * mean;
    float inv  = rsqrtf(var + 1e-12f);
    #pragma unroll
    for (int i = 0; i < 3; ++i) {
        int c = tid + 256 * i;
        float v = (vals[i] - mean) * inv * g[c] + bb[c];
        out[(long)t * H_ + c] = v;
        outb[(long)t * H_ + c] = __float2bfloat16(v);
    }
}

// -------------------- bf16 MFMA GEMM (m97 structure) --------------------
// C[M,N] = A[M,K](bf16) * BT[N,K]^T(bf16) + bias, optional GELU,
// writes f32 and/or bf16. 128x128 tile, BK=32, 4 waves, global_load_lds w=16.
template<int ACT, int WF32, int WB16>
__global__ __launch_bounds__(256, 2) void mfma_gemm_kernel(
    const __hip_bfloat16* __restrict__ A,
    const __hip_bfloat16* __restrict__ BT,
    const float* __restrict__ bias,
    float* __restrict__ Cf,
    __hip_bfloat16* __restrict__ Cb,
    int M, int N, int K) {
    __shared__ __align__(16) __hip_bfloat16 sA[128 * 32];
    __shared__ __align__(16) __hip_bfloat16 sB[128 * 32];
    const int tid  = threadIdx.x;
    const int lane = tid & 63;
    const int w    = tid >> 6;
    const int wr   = w >> 1, wc = w & 1;
    const int m0 = blockIdx.y * 128, n0 = blockIdx.x * 128;
    const int c0 = tid, c1 = tid + 256;          // staging chunk ids (16B each)
    const int r0 = c0 >> 2, g0 = (c0 & 3) * 8;   // row / col8 within tile
    const int r1 = c1 >> 2, g1 = (c1 & 3) * 8;

    f32x4 acc[4][4] = {};

    for (int k0 = 0; k0 < K; k0 += 32) {
        gload16(A  + (long)(m0 + r0) * K + k0 + g0, sA + c0 * 8);
        gload16(A  + (long)(m0 + r1) * K + k0 + g1, sA + c1 * 8);
        gload16(BT + (long)(n0 + r0) * K + k0 + g0, sB + c0 * 8);
        gload16(BT + (long)(n0 + r1) * K + k0 + g1, sB + c1 * 8);
        __syncthreads();
        const int kk = (lane >> 4) * 8;
        bf16x8 af[4], bf[4];
        #pragma unroll
        for (int i = 0; i < 4; ++i) {
            af[i] = *reinterpret_cast<const bf16x8*>(sA + (wr * 64 + i * 16 + (lane & 15)) * 32 + kk);
            bf[i] = *reinterpret_cast<const bf16x8*>(sB + (wc * 64 + i * 16 + (lane & 15)) * 32 + kk);
        }
        #pragma unroll
        for (int i = 0; i < 4; ++i)
            #pragma unroll
            for (int j = 0; j < 4; ++j)
                acc[i][j] = __builtin_amdgcn_mfma_f32_16x16x32_bf16(af[i], bf[j], acc[i][j], 0, 0, 0);
        __syncthreads();
    }

    #pragma unroll
    for (int i = 0; i < 4; ++i) {
        #pragma unroll
        for (int j = 0; j < 4; ++j) {
            int col = n0 + wc * 64 + j * 16 + (lane & 15);
            float bv = bias[col];
            #pragma unroll
            for (int r = 0; r < 4; ++r) {
                int row = m0 + wr * 64 + i * 16 + (lane >> 4) * 4 + r;
                float v = acc[i][j][r] + bv;
                if (ACT == 1) v = gelu_exact(v);
                if (WF32) Cf[(long)row * N + col] = v;
                if (WB16) Cb[(long)row * N + col] = __float2bfloat16(v);
            }
        }
    }
}

// -------------------- f32 GEMM (pooled head only, M=8) --------------------
template<int ACT>
__global__ void gemm_bias_kernel(const float* __restrict__ A, int lda,
                                 const float* __restrict__ Bm,
                                 const float* __restrict__ bias,
                                 float* __restrict__ C,
                                 int M, int N, int K) {
    __shared__ float As[64][17];
    __shared__ float Bs[16][65];
    int tid = threadIdx.x;
    int tx = tid & 15, ty = tid >> 4;
    int m0 = blockIdx.y * 64, n0 = blockIdx.x * 64;
    int br = tid >> 6, bc = tid & 63;
    float acc[4][4] = {};
    for (int k0 = 0; k0 < K; k0 += 16) {
        #pragma unroll
        for (int i = 0; i < 4; ++i) {
            int r = m0 + ty + 16 * i;
            As[ty + 16 * i][tx] = (r < M) ? A[(long)r * lda + k0 + tx] : 0.f;
        }
        #pragma unroll
        for (int i = 0; i < 4; ++i)
            Bs[br + 4 * i][bc] = Bm[(long)(k0 + br + 4 * i) * N + n0 + bc];
        __syncthreads();
        #pragma unroll
        for (int kk = 0; kk < 16; ++kk) {
            float a[4], bv[4];
            #pragma unroll
            for (int i = 0; i < 4; ++i) a[i] = As[ty + 16 * i][kk];
            #pragma unroll
            for (int j = 0; j < 4; ++j) bv[j] = Bs[kk][tx + 16 * j];
            #pragma unroll
            for (int i = 0; i < 4; ++i)
                #pragma unroll
                for (int j = 0; j < 4; ++j) acc[i][j] += a[i] * bv[j];
        }
        __syncthreads();
    }
    #pragma unroll
    for (int i = 0; i < 4; ++i) {
        int row = m0 + ty + 16 * i;
        if (row >= M) continue;
        #pragma unroll
        for (int j = 0; j < 4; ++j) {
            int col = n0 + tx + 16 * j;
            float v = acc[i][j] + bias[col];
            if (ACT == 1) v = gelu_exact(v);
            C[(long)row * N + col] = v;
        }
    }
}

// -------------------- scores[bh,i,j] = scale * Q.K --------------------
__global__ void attn_scores_kernel(const float* __restrict__ q,
                                   const float* __restrict__ k,
                                   float* __restrict__ scores,
                                   float scale) {
    int bh = blockIdx.z;
    int b = bh / NH_, hd = bh % NH_;
    long base  = (long)b * S_ * H_ + hd * D_;
    long sbase = (long)bh * S_ * S_;
    int q0 = blockIdx.y * 64, k0 = blockIdx.x * 64;
    __shared__ float Qs[64][65], Ks[64][65];
    int tid = threadIdx.x;
    int lr = tid >> 6, lc = tid & 63;
    #pragma unroll
    for (int i = 0; i < 16; ++i) {
        int r = lr + 4 * i;
        Qs[r][lc] = q[base + (long)(q0 + r) * H_ + lc];
        Ks[r][lc] = k[base + (long)(k0 + r) * H_ + lc];
    }
    __syncthreads();
    int tx = tid & 15, ty = tid >> 4;
    float acc[4][4] = {};
    #pragma unroll 4
    for (int kk = 0; kk < 64; ++kk) {
        float a[4], bv[4];
        #pragma unroll
        for (int i = 0; i < 4; ++i) a[i] = Qs[ty + 16 * i][kk];
        #pragma unroll
        for (int j = 0; j < 4; ++j) bv[j] = Ks[tx + 16 * j][kk];
        #pragma unroll
        for (int i = 0; i < 4; ++i)
            #pragma unroll
            for (int j = 0; j < 4; ++j) acc[i][j] += a[i] * bv[j];
    }
    #pragma unroll
    for (int i = 0; i < 4; ++i)
        #pragma unroll
        for (int j = 0; j < 4; ++j)
            scores[sbase + (long)(q0 + ty + 16 * i) * S_ + k0 + tx + 16 * j] = acc[i][j] * scale;
}

// -------------------- row softmax, one wave per row --------------------
__global__ void softmax_kernel(float* __restrict__ scores) {
    long row = blockIdx.x;
    int lane = threadIdx.x;
    float* p = scores + row * S_;
    float x[8];
    float mx = -1e30f;
    #pragma unroll
    for (int i = 0; i < 8; ++i) { x[i] = p[lane + 64 * i]; mx = fmaxf(mx, x[i]); }
    #pragma unroll
    for (int o = 32; o > 0; o >>= 1) mx = fmaxf(mx, __shfl_xor(mx, o));
    float sum = 0.f;
    #pragma unroll
    for (int i = 0; i < 8; ++i) { x[i] = expf(x[i] - mx); sum += x[i]; }
    #pragma unroll
    for (int o = 32; o > 0; o >>= 1) sum += __shfl_xor(sum, o);
    float inv = 1.f / sum;
    #pragma unroll
    for (int i = 0; i < 8; ++i) p[lane + 64 * i] = x[i] * inv;
}

// -------------------- ctx = P @ V, bf16 out --------------------
__global__ void attn_ctx_kernel(const float* __restrict__ probs,
                                const float* __restrict__ v,
                                __hip_bfloat16* __restrict__ ctx) {
    int bh = blockIdx.z;
    int b = bh / NH_, hd = bh % NH_;
    long vbase = (long)b * S_ * H_ + hd * D_;
    long sbase = (long)bh * S_ * S_;
    int q0 = blockIdx.y * 64;
    __shared__ float Ps[64][17], Vs[16][65];
    int tid = threadIdx.x;
    int tx = tid & 15, ty = tid >> 4;
    int br = tid >> 6, bc = tid & 63;
    float acc[4][4] = {};
    for (int k0 = 0; k0 < S_; k0 += 16) {
        #pragma unroll
        for (int i = 0; i < 4; ++i)
            Ps[ty + 16 * i][tx] = probs[sbase + (long)(q0 + ty + 16 * i) * S_ + k0 + tx];
        #pragma unroll
        for (int i = 0; i < 4; ++i)
            Vs[br + 4 * i][bc] = v[vbase + (long)(k0 + br + 4 * i) * H_ + bc];
        __syncthreads();
        #pragma unroll
        for (int kk = 0; kk < 16; ++kk) {
            float a[4], bv[4];
            #pragma unroll
            for (int i = 0; i < 4; ++i) a[i] = Ps[ty + 16 * i][kk];
            #pragma unroll
            for (int j = 0; j < 4; ++j) bv[j] = Vs[kk][tx + 16 * j];
            #pragma unroll
            for (int i = 0; i < 4; ++i)
                #pragma unroll
                for (int j = 0; j < 4; ++j) acc[i][j] += a[i] * bv[j];
        }
        __syncthreads();
    }
    #pragma unroll
    for (int i = 0; i < 4; ++i)
        #pragma unroll
        for (int j = 0; j < 4; ++j)
            ctx[(long)b * S_ * H_ + (long)(q0 + ty + 16 * i) * H_ + hd * D_ + tx + 16 * j] =
                __float2bfloat16(acc[i][j]);
}

extern "C" void kernel_launch(void* const* d_in, const int* in_sizes, int n_in,
                              void* d_out, int out_size, void* d_ws, size_t ws_size,
                              hipStream_t stream) {
    const int*   x      = (const int*)  d_in[0];
    const float* W_word = (const float*)d_in[1];
    const float* W_pos  = (const float*)d_in[2];
    const float* W_type = (const float*)d_in[3];
    const float* g_emb  = (const float*)d_in[4];
    const float* b_emb  = (const float*)d_in[5];
    const float* Wq     = (const float*)d_in[6];
    const float* bq     = (const float*)d_in[7];
    const float* Wk     = (const float*)d_in[8];
    const float* bk     = (const float*)d_in[9];
    const float* Wv     = (const float*)d_in[10];
    const float* bv     = (const float*)d_in[11];
    const float* Wo     = (const float*)d_in[12];
    const float* bo     = (const float*)d_in[13];
    const float* g_attn = (const float*)d_in[14];
    const float* b_attn = (const float*)d_in[15];
    const float* Wi     = (const float*)d_in[16];
    const float* bi     = (const float*)d_in[17];
    const float* Wd     = (const float*)d_in[18];
    const float* bd     = (const float*)d_in[19];
    const float* g_out  = (const float*)d_in[20];
    const float* b_out  = (const float*)d_in[21];
    const float* Wp     = (const float*)d_in[22];
    const float* bp     = (const float*)d_in[23];

    const size_t NT = (size_t)NTOK * H_;        // 3,145,728
    char* base = (char*)d_ws;
    size_t off = 0;
    auto alloc = [&](size_t bytes) -> char* {
        char* p = base + off;
        off += (bytes + 255) & ~(size_t)255;
        return p;
    };
    float* h    = (float*)alloc(NT * 4);
    float* xa   = (float*)alloc(NT * 4);
    float* qb   = (float*)alloc(NT * 4);
    float* kb   = (float*)alloc(NT * 4);  // k proj; then O-proj out; then FF2 out
    float* vb   = (float*)alloc(NT * 4);
    float* big  = (float*)alloc((size_t)B_ * NH_ * S_ * S_ * 4);  // scores; reused as ff1_b (bf16)
    __hip_bfloat16* h_b   = (__hip_bfloat16*)alloc(NT * 2);
    __hip_bfloat16* xa_b  = (__hip_bfloat16*)alloc(NT * 2);
    __hip_bfloat16* ctx_b = (__hip_bfloat16*)alloc(NT * 2);
    __hip_bfloat16* WqT = (__hip_bfloat16*)alloc((size_t)H_ * H_ * 2);
    __hip_bfloat16* WkT = (__hip_bfloat16*)alloc((size_t)H_ * H_ * 2);
    __hip_bfloat16* WvT = (__hip_bfloat16*)alloc((size_t)H_ * H_ * 2);
    __hip_bfloat16* WoT = (__hip_bfloat16*)alloc((size_t)H_ * H_ * 2);
    __hip_bfloat16* WiT = (__hip_bfloat16*)alloc((size_t)H_ * I_ * 2);
    __hip_bfloat16* WdT = (__hip_bfloat16*)alloc((size_t)I_ * H_ * 2);
    __hip_bfloat16* ff1_b = (__hip_bfloat16*)big;

    // one-time (per launch) weight transpose+convert
    cvtT_kernel<<<dim3(H_/32, H_/32), 256, 0, stream>>>(Wq, WqT, H_, H_);
    cvtT_kernel<<<dim3(H_/32, H_/32), 256, 0, stream>>>(Wk, WkT, H_, H_);
    cvtT_kernel<<<dim3(H_/32, H_/32), 256, 0, stream>>>(Wv, WvT, H_, H_);
    cvtT_kernel<<<dim3(H_/32, H_/32), 256, 0, stream>>>(Wo, WoT, H_, H_);
    cvtT_kernel<<<dim3(I_/32, H_/32), 256, 0, stream>>>(Wi, WiT, H_, I_);
    cvtT_kernel<<<dim3(H_/32, I_/32), 256, 0, stream>>>(Wd, WdT, I_, H_);

    embed_ln_kernel<<<NTOK, 256, 0, stream>>>(x, W_word, W_pos, W_type, g_emb, b_emb, h, h_b);

    const float scale = 0.125f;
    dim3 gq(H_/128, NTOK/128);   // (6, 32)
    dim3 gi(I_/128, NTOK/128);   // (24, 32)
    for (int layer = 0; layer < 6; ++layer) {
        mfma_gemm_kernel<0,1,0><<<gq, 256, 0, stream>>>(h_b, WqT, bq, qb, nullptr, NTOK, H_, H_);
        mfma_gemm_kernel<0,1,0><<<gq, 256, 0, stream>>>(h_b, WkT, bk, kb, nullptr, NTOK, H_, H_);
        mfma_gemm_kernel<0,1,0><<<gq, 256, 0, stream>>>(h_b, WvT, bv, vb, nullptr, NTOK, H_, H_);
        attn_scores_kernel<<<dim3(8, 8, B_ * NH_), 256, 0, stream>>>(qb, kb, big, scale);
        softmax_kernel<<<dim3(B_ * NH_ * S_), 64, 0, stream>>>(big);
        attn_ctx_kernel<<<dim3(1, 8, B_ * NH_), 256, 0, stream>>>(big, vb, ctx_b);
        mfma_gemm_kernel<0,1,0><<<gq, 256, 0, stream>>>(ctx_b, WoT, bo, kb, nullptr, NTOK, H_, H_);
        add_ln_kernel<<<NTOK, 256, 0, stream>>>(h, kb, g_attn, b_attn, xa, xa_b);
        mfma_gemm_kernel<1,0,1><<<gi, 256, 0, stream>>>(xa_b, WiT, bi, nullptr, ff1_b, NTOK, I_, H_);
        mfma_gemm_kernel<0,1,0><<<gq, 256, 0, stream>>>(ff1_b, WdT, bd, kb, nullptr, NTOK, H_, I_);
        add_ln_kernel<<<NTOK, 256, 0, stream>>>(xa, kb, g_out, b_out, h, h_b);
    }

    hipMemcpyAsync(d_out, h, NT * sizeof(float), hipMemcpyDeviceToDevice, stream);
    gemm_bias_kernel<0><<<dim3(12, 1), 256, 0, stream>>>(h, S_ * H_, Wp, bp,
                                                         (float*)d_out + NT, B_, H_, H_);
}

// Round 3
// 1476.429 us; speedup vs baseline: 5.6885x; 1.4954x over previous
//
#include <hip/hip_runtime.h>
#include <hip/hip_bf16.h>
#include <math.h>

#define B_  8
#define S_  512
#define H_  768
#define NH_ 12
#define D_  64
#define I_  3072
#define NTOK (B_*S_)   // 4096

typedef __attribute__((ext_vector_type(8))) __bf16 bf16x8;
typedef __attribute__((ext_vector_type(8))) unsigned short ushort8;
typedef __attribute__((ext_vector_type(4))) float  f32x4;

__device__ __forceinline__ float gelu_exact(float x) {
    return 0.5f * x * (1.0f + erff(x * 0.70710678118654752440f));
}

__device__ __forceinline__ unsigned short f2bf(float x) {
    __hip_bfloat16 h = __float2bfloat16(x);
    return *reinterpret_cast<unsigned short*>(&h);
}

__device__ __forceinline__ void gload16(const void* g, void* l) {
    __builtin_amdgcn_global_load_lds(
        (const __attribute__((address_space(1))) void*)g,
        (__attribute__((address_space(3))) void*)l,
        16, 0, 0);
}

// -------------------- f32 [K][N] -> bf16 [N][K] transpose-convert --------------------
__global__ void cvtT_kernel(const float* __restrict__ W, __hip_bfloat16* __restrict__ WT,
                            int K, int N) {
    __shared__ float tile[32][33];
    int k0 = blockIdx.y * 32, n0 = blockIdx.x * 32;
    int tx = threadIdx.x & 31, ty = threadIdx.x >> 5;   // 32x8
    #pragma unroll
    for (int i = 0; i < 32; i += 8)
        tile[ty + i][tx] = W[(long)(k0 + ty + i) * N + n0 + tx];
    __syncthreads();
    #pragma unroll
    for (int i = 0; i < 32; i += 8)
        WT[(long)(n0 + ty + i) * K + k0 + tx] = __float2bfloat16(tile[tx][ty + i]);
}

// -------------------- embeddings + LayerNorm (f32 + bf16 outputs) --------------------
__global__ void embed_ln_kernel(const int* __restrict__ ids,
                                const float* __restrict__ Wword,
                                const float* __restrict__ Wpos,
                                const float* __restrict__ Wtype,
                                const float* __restrict__ g,
                                const float* __restrict__ b,
                                float* __restrict__ out,
                                __hip_bfloat16* __restrict__ outb) {
    int t = blockIdx.x;
    int s = t % S_;
    long id = ids[t];
    int tid = threadIdx.x;
    float vals[3];
    float sum = 0.f, sq = 0.f;
    #pragma unroll
    for (int i = 0; i < 3; ++i) {
        int c = tid + 256 * i;
        float e = Wword[id * H_ + c] + Wpos[(long)s * H_ + c] + Wtype[c];
        vals[i] = e; sum += e; sq += e * e;
    }
    __shared__ float r1[256], r2[256];
    r1[tid] = sum; r2[tid] = sq; __syncthreads();
    for (int st = 128; st > 0; st >>= 1) {
        if (tid < st) { r1[tid] += r1[tid + st]; r2[tid] += r2[tid + st]; }
        __syncthreads();
    }
    float mean = r1[0] * (1.0f / H_);
    float var  = r2[0] * (1.0f / H_) - mean * mean;
    float inv  = rsqrtf(var + 1e-12f);
    #pragma unroll
    for (int i = 0; i < 3; ++i) {
        int c = tid + 256 * i;
        float v = (vals[i] - mean) * inv * g[c] + b[c];
        out[(long)t * H_ + c] = v;
        outb[(long)t * H_ + c] = __float2bfloat16(v);
    }
}

// -------------------- LN(a + r) (f32 + bf16 outputs) --------------------
__global__ void add_ln_kernel(const float* __restrict__ a,
                              const float* __restrict__ r,
                              const float* __restrict__ g,
                              const float* __restrict__ bb,
                              float* __restrict__ out,
                              __hip_bfloat16* __restrict__ outb) {
    int t = blockIdx.x;
    int tid = threadIdx.x;
    float vals[3];
    float sum = 0.f, sq = 0.f;
    #pragma unroll
    for (int i = 0; i < 3; ++i) {
        int c = tid + 256 * i;
        float e = a[(long)t * H_ + c] + r[(long)t * H_ + c];
        vals[i] = e; sum += e; sq += e * e;
    }
    __shared__ float r1[256], r2[256];
    r1[tid] = sum; r2[tid] = sq; __syncthreads();
    for (int st = 128; st > 0; st >>= 1) {
        if (tid < st) { r1[tid] += r1[tid + st]; r2[tid] += r2[tid + st]; }
        __syncthreads();
    }
    float mean = r1[0] * (1.0f / H_);
    float var  = r2[0] * (1.0f / H_) - mean * mean;
    float inv  = rsqrtf(var + 1e-12f);
    #pragma unroll
    for (int i = 0; i < 3; ++i) {
        int c = tid + 256 * i;
        float v = (vals[i] - mean) * inv * g[c] + bb[c];
        out[(long)t * H_ + c] = v;
        outb[(long)t * H_ + c] = __float2bfloat16(v);
    }
}

// -------------------- bf16 MFMA GEMM (m97 structure) --------------------
template<int ACT, int WF32, int WB16>
__global__ __launch_bounds__(256, 2) void mfma_gemm_kernel(
    const __hip_bfloat16* __restrict__ A,
    const __hip_bfloat16* __restrict__ BT,
    const float* __restrict__ bias,
    float* __restrict__ Cf,
    __hip_bfloat16* __restrict__ Cb,
    int M, int N, int K) {
    __shared__ __align__(16) __hip_bfloat16 sA[128 * 32];
    __shared__ __align__(16) __hip_bfloat16 sB[128 * 32];
    const int tid  = threadIdx.x;
    const int lane = tid & 63;
    const int w    = tid >> 6;
    const int wr   = w >> 1, wc = w & 1;
    const int m0 = blockIdx.y * 128, n0 = blockIdx.x * 128;
    const int c0 = tid, c1 = tid + 256;
    const int r0 = c0 >> 2, g0 = (c0 & 3) * 8;
    const int r1 = c1 >> 2, g1 = (c1 & 3) * 8;

    f32x4 acc[4][4] = {};

    for (int k0 = 0; k0 < K; k0 += 32) {
        gload16(A  + (long)(m0 + r0) * K + k0 + g0, sA + c0 * 8);
        gload16(A  + (long)(m0 + r1) * K + k0 + g1, sA + c1 * 8);
        gload16(BT + (long)(n0 + r0) * K + k0 + g0, sB + c0 * 8);
        gload16(BT + (long)(n0 + r1) * K + k0 + g1, sB + c1 * 8);
        __syncthreads();
        const int kk = (lane >> 4) * 8;
        bf16x8 af[4], bf[4];
        #pragma unroll
        for (int i = 0; i < 4; ++i) {
            af[i] = *reinterpret_cast<const bf16x8*>(sA + (wr * 64 + i * 16 + (lane & 15)) * 32 + kk);
            bf[i] = *reinterpret_cast<const bf16x8*>(sB + (wc * 64 + i * 16 + (lane & 15)) * 32 + kk);
        }
        #pragma unroll
        for (int i = 0; i < 4; ++i)
            #pragma unroll
            for (int j = 0; j < 4; ++j)
                acc[i][j] = __builtin_amdgcn_mfma_f32_16x16x32_bf16(af[i], bf[j], acc[i][j], 0, 0, 0);
        __syncthreads();
    }

    #pragma unroll
    for (int i = 0; i < 4; ++i) {
        #pragma unroll
        for (int j = 0; j < 4; ++j) {
            int col = n0 + wc * 64 + j * 16 + (lane & 15);
            float bv = bias[col];
            #pragma unroll
            for (int r = 0; r < 4; ++r) {
                int row = m0 + wr * 64 + i * 16 + (lane >> 4) * 4 + r;
                float v = acc[i][j][r] + bv;
                if (ACT == 1) v = gelu_exact(v);
                if (WF32) Cf[(long)row * N + col] = v;
                if (WB16) Cb[(long)row * N + col] = __float2bfloat16(v);
            }
        }
    }
}

// -------------------- fused flash attention (bf16 MFMA, online softmax) --------------------
// grid (S/64, B*NH); block 256 = 4 waves; wave handles 16 q-rows.
__global__ __launch_bounds__(256, 4) void flash_attn_kernel(
    const __hip_bfloat16* __restrict__ Qb,
    const __hip_bfloat16* __restrict__ Kb,
    const __hip_bfloat16* __restrict__ Vb,
    __hip_bfloat16* __restrict__ Ctx) {
    __shared__ __align__(16) unsigned short sK[64 * 72];   // K tile [kv][d], pad 8
    __shared__ __align__(16) unsigned short sVt[64 * 72];  // V^T tile [d][kv], pad 8
    __shared__ __align__(16) unsigned short sP[4 * 16 * 72]; // per-wave P [q][kv], pad 8

    const int tid  = threadIdx.x;
    const int lane = tid & 63;
    const int w    = tid >> 6;
    const int l15  = lane & 15, l4 = lane >> 4;
    const int qb = blockIdx.x;           // 0..7
    const int bh = blockIdx.y;           // 0..95
    const int b  = bh / NH_, hd = bh % NH_;
    const long hbase = (long)b * S_ * H_ + hd * D_;

    // Q fragments for this wave's 16 rows (kept in regs for whole KV loop)
    const int qrow0 = qb * 64 + w * 16;
    bf16x8 af[2];
    #pragma unroll
    for (int ks = 0; ks < 2; ++ks)
        af[ks] = *reinterpret_cast<const bf16x8*>(Qb + hbase + (long)(qrow0 + l15) * H_ + ks * 32 + l4 * 8);

    f32x4 ctx[4] = {};
    float m_run[4], l_run[4];
    #pragma unroll
    for (int r = 0; r < 4; ++r) { m_run[r] = -1e30f; l_run[r] = 0.f; }

    const int sr = tid >> 2;          // staging row 0..63
    const int sc = (tid & 3) * 16;    // staging elem col 0,16,32,48
    unsigned short* pl = sP + w * (16 * 72);

    for (int kv0 = 0; kv0 < S_; kv0 += 64) {
        // issue global loads early (hide under barrier)
        const __hip_bfloat16* kg = Kb + hbase + (long)(kv0 + sr) * H_ + sc;
        const __hip_bfloat16* vg = Vb + hbase + (long)(kv0 + sr) * H_ + sc;
        ushort8 kv_a = *reinterpret_cast<const ushort8*>(kg);
        ushort8 kv_b = *reinterpret_cast<const ushort8*>(kg + 8);
        ushort8 vv_a = *reinterpret_cast<const ushort8*>(vg);
        ushort8 vv_b = *reinterpret_cast<const ushort8*>(vg + 8);
        __syncthreads();   // previous iteration's consumers done
        *reinterpret_cast<ushort8*>(sK + sr * 72 + sc)     = kv_a;
        *reinterpret_cast<ushort8*>(sK + sr * 72 + sc + 8) = kv_b;
        #pragma unroll
        for (int i = 0; i < 8; ++i) {
            sVt[(sc + i) * 72 + sr]     = vv_a[i];
            sVt[(sc + 8 + i) * 72 + sr] = vv_b[i];
        }
        __syncthreads();

        // S = Q K^T  (rows q=(l>>4)*4+r, cols kv=l15+16j)
        f32x4 s[4];
        #pragma unroll
        for (int j = 0; j < 4; ++j) {
            s[j] = (f32x4){0.f, 0.f, 0.f, 0.f};
            #pragma unroll
            for (int ks = 0; ks < 2; ++ks) {
                bf16x8 bk = *reinterpret_cast<const bf16x8*>(sK + (j * 16 + l15) * 72 + ks * 32 + l4 * 8);
                s[j] = __builtin_amdgcn_mfma_f32_16x16x32_bf16(af[ks], bk, s[j], 0, 0, 0);
            }
        }
        #pragma unroll
        for (int j = 0; j < 4; ++j) s[j] *= 0.125f;   // 1/sqrt(D)

        // online softmax (reduce over lane bits 0-3 = kv cols)
        #pragma unroll
        for (int r = 0; r < 4; ++r) {
            float mx = fmaxf(fmaxf(s[0][r], s[1][r]), fmaxf(s[2][r], s[3][r]));
            #pragma unroll
            for (int o = 1; o < 16; o <<= 1) mx = fmaxf(mx, __shfl_xor(mx, o));
            float mnew = fmaxf(m_run[r], mx);
            float sum = 0.f;
            #pragma unroll
            for (int j = 0; j < 4; ++j) {
                float p = __expf(s[j][r] - mnew);
                s[j][r] = p; sum += p;
            }
            #pragma unroll
            for (int o = 1; o < 16; o <<= 1) sum += __shfl_xor(sum, o);
            float resc = __expf(m_run[r] - mnew);
            l_run[r] = l_run[r] * resc + sum;
            m_run[r] = mnew;
            #pragma unroll
            for (int j = 0; j < 4; ++j) ctx[j][r] *= resc;
        }

        // P -> per-wave LDS (layout change C/D -> A-frag), bf16
        #pragma unroll
        for (int j = 0; j < 4; ++j)
            #pragma unroll
            for (int r = 0; r < 4; ++r)
                pl[(l4 * 4 + r) * 72 + j * 16 + l15] = f2bf(s[j][r]);

        // ctx += P @ V   (A = P rows q=l15; B = V^T rows d=l15+16jd)
        #pragma unroll
        for (int ks = 0; ks < 2; ++ks) {
            bf16x8 ap = *reinterpret_cast<const bf16x8*>(pl + l15 * 72 + ks * 32 + l4 * 8);
            #pragma unroll
            for (int jd = 0; jd < 4; ++jd) {
                bf16x8 bv = *reinterpret_cast<const bf16x8*>(sVt + (jd * 16 + l15) * 72 + ks * 32 + l4 * 8);
                ctx[jd] = __builtin_amdgcn_mfma_f32_16x16x32_bf16(ap, bv, ctx[jd], 0, 0, 0);
            }
        }
    }

    // epilogue: normalize and store bf16 ctx in (B,S,H)
    #pragma unroll
    for (int r = 0; r < 4; ++r) {
        float inv = 1.f / l_run[r];
        long tok = (long)b * S_ + qb * 64 + w * 16 + l4 * 4 + r;
        #pragma unroll
        for (int jd = 0; jd < 4; ++jd)
            Ctx[tok * H_ + hd * D_ + jd * 16 + l15] = __float2bfloat16(ctx[jd][r] * inv);
    }
}

// -------------------- f32 GEMM (pooled head only, M=8) --------------------
template<int ACT>
__global__ void gemm_bias_kernel(const float* __restrict__ A, int lda,
                                 const float* __restrict__ Bm,
                                 const float* __restrict__ bias,
                                 float* __restrict__ C,
                                 int M, int N, int K) {
    __shared__ float As[64][17];
    __shared__ float Bs[16][65];
    int tid = threadIdx.x;
    int tx = tid & 15, ty = tid >> 4;
    int m0 = blockIdx.y * 64, n0 = blockIdx.x * 64;
    int br = tid >> 6, bc = tid & 63;
    float acc[4][4] = {};
    for (int k0 = 0; k0 < K; k0 += 16) {
        #pragma unroll
        for (int i = 0; i < 4; ++i) {
            int r = m0 + ty + 16 * i;
            As[ty + 16 * i][tx] = (r < M) ? A[(long)r * lda + k0 + tx] : 0.f;
        }
        #pragma unroll
        for (int i = 0; i < 4; ++i)
            Bs[br + 4 * i][bc] = Bm[(long)(k0 + br + 4 * i) * N + n0 + bc];
        __syncthreads();
        #pragma unroll
        for (int kk = 0; kk < 16; ++kk) {
            float a[4], bv[4];
            #pragma unroll
            for (int i = 0; i < 4; ++i) a[i] = As[ty + 16 * i][kk];
            #pragma unroll
            for (int j = 0; j < 4; ++j) bv[j] = Bs[kk][tx + 16 * j];
            #pragma unroll
            for (int i = 0; i < 4; ++i)
                #pragma unroll
                for (int j = 0; j < 4; ++j) acc[i][j] += a[i] * bv[j];
        }
        __syncthreads();
    }
    #pragma unroll
    for (int i = 0; i < 4; ++i) {
        int row = m0 + ty + 16 * i;
        if (row >= M) continue;
        #pragma unroll
        for (int j = 0; j < 4; ++j) {
            int col = n0 + tx + 16 * j;
            float v = acc[i][j] + bias[col];
            if (ACT == 1) v = gelu_exact(v);
            C[(long)row * N + col] = v;
        }
    }
}

extern "C" void kernel_launch(void* const* d_in, const int* in_sizes, int n_in,
                              void* d_out, int out_size, void* d_ws, size_t ws_size,
                              hipStream_t stream) {
    const int*   x      = (const int*)  d_in[0];
    const float* W_word = (const float*)d_in[1];
    const float* W_pos  = (const float*)d_in[2];
    const float* W_type = (const float*)d_in[3];
    const float* g_emb  = (const float*)d_in[4];
    const float* b_emb  = (const float*)d_in[5];
    const float* Wq     = (const float*)d_in[6];
    const float* bq     = (const float*)d_in[7];
    const float* Wk     = (const float*)d_in[8];
    const float* bk     = (const float*)d_in[9];
    const float* Wv     = (const float*)d_in[10];
    const float* bv     = (const float*)d_in[11];
    const float* Wo     = (const float*)d_in[12];
    const float* bo     = (const float*)d_in[13];
    const float* g_attn = (const float*)d_in[14];
    const float* b_attn = (const float*)d_in[15];
    const float* Wi     = (const float*)d_in[16];
    const float* bi     = (const float*)d_in[17];
    const float* Wd     = (const float*)d_in[18];
    const float* bd     = (const float*)d_in[19];
    const float* g_out  = (const float*)d_in[20];
    const float* b_out  = (const float*)d_in[21];
    const float* Wp     = (const float*)d_in[22];
    const float* bp     = (const float*)d_in[23];

    const size_t NT = (size_t)NTOK * H_;
    char* base = (char*)d_ws;
    size_t off = 0;
    auto alloc = [&](size_t bytes) -> char* {
        char* p = base + off;
        off += (bytes + 255) & ~(size_t)255;
        return p;
    };
    float* h    = (float*)alloc(NT * 4);
    float* xa   = (float*)alloc(NT * 4);
    float* kb   = (float*)alloc(NT * 4);  // O-proj / FF2 f32 out
    __hip_bfloat16* h_b   = (__hip_bfloat16*)alloc(NT * 2);
    __hip_bfloat16* xa_b  = (__hip_bfloat16*)alloc(NT * 2);
    __hip_bfloat16* q_b   = (__hip_bfloat16*)alloc(NT * 2);
    __hip_bfloat16* k_b   = (__hip_bfloat16*)alloc(NT * 2);
    __hip_bfloat16* v_b   = (__hip_bfloat16*)alloc(NT * 2);
    __hip_bfloat16* ctx_b = (__hip_bfloat16*)alloc(NT * 2);
    __hip_bfloat16* ff1_b = (__hip_bfloat16*)alloc((size_t)NTOK * I_ * 2);
    __hip_bfloat16* WqT = (__hip_bfloat16*)alloc((size_t)H_ * H_ * 2);
    __hip_bfloat16* WkT = (__hip_bfloat16*)alloc((size_t)H_ * H_ * 2);
    __hip_bfloat16* WvT = (__hip_bfloat16*)alloc((size_t)H_ * H_ * 2);
    __hip_bfloat16* WoT = (__hip_bfloat16*)alloc((size_t)H_ * H_ * 2);
    __hip_bfloat16* WiT = (__hip_bfloat16*)alloc((size_t)H_ * I_ * 2);
    __hip_bfloat16* WdT = (__hip_bfloat16*)alloc((size_t)I_ * H_ * 2);

    cvtT_kernel<<<dim3(H_/32, H_/32), 256, 0, stream>>>(Wq, WqT, H_, H_);
    cvtT_kernel<<<dim3(H_/32, H_/32), 256, 0, stream>>>(Wk, WkT, H_, H_);
    cvtT_kernel<<<dim3(H_/32, H_/32), 256, 0, stream>>>(Wv, WvT, H_, H_);
    cvtT_kernel<<<dim3(H_/32, H_/32), 256, 0, stream>>>(Wo, WoT, H_, H_);
    cvtT_kernel<<<dim3(I_/32, H_/32), 256, 0, stream>>>(Wi, WiT, H_, I_);
    cvtT_kernel<<<dim3(H_/32, I_/32), 256, 0, stream>>>(Wd, WdT, I_, H_);

    embed_ln_kernel<<<NTOK, 256, 0, stream>>>(x, W_word, W_pos, W_type, g_emb, b_emb, h, h_b);

    dim3 gq(H_/128, NTOK/128);   // (6, 32)
    dim3 gi(I_/128, NTOK/128);   // (24, 32)
    for (int layer = 0; layer < 6; ++layer) {
        mfma_gemm_kernel<0,0,1><<<gq, 256, 0, stream>>>(h_b, WqT, bq, nullptr, q_b, NTOK, H_, H_);
        mfma_gemm_kernel<0,0,1><<<gq, 256, 0, stream>>>(h_b, WkT, bk, nullptr, k_b, NTOK, H_, H_);
        mfma_gemm_kernel<0,0,1><<<gq, 256, 0, stream>>>(h_b, WvT, bv, nullptr, v_b, NTOK, H_, H_);
        flash_attn_kernel<<<dim3(S_/64, B_*NH_), 256, 0, stream>>>(q_b, k_b, v_b, ctx_b);
        mfma_gemm_kernel<0,1,0><<<gq, 256, 0, stream>>>(ctx_b, WoT, bo, kb, nullptr, NTOK, H_, H_);
        add_ln_kernel<<<NTOK, 256, 0, stream>>>(h, kb, g_attn, b_attn, xa, xa_b);
        mfma_gemm_kernel<1,0,1><<<gi, 256, 0, stream>>>(xa_b, WiT, bi, nullptr, ff1_b, NTOK, I_, H_);
        mfma_gemm_kernel<0,1,0><<<gq, 256, 0, stream>>>(ff1_b, WdT, bd, kb, nullptr, NTOK, H_, I_);
        add_ln_kernel<<<NTOK, 256, 0, stream>>>(xa, kb, g_out, b_out, h, h_b);
    }

    hipMemcpyAsync(d_out, h, NT * sizeof(float), hipMemcpyDeviceToDevice, stream);
    gemm_bias_kernel<0><<<dim3(12, 1), 256, 0, stream>>>(h, S_ * H_, Wp, bp,
                                                         (float*)d_out + NT, B_, H_, H_);
}

// Round 4
// 1173.307 us; speedup vs baseline: 7.1581x; 1.2583x over previous
//
#include <hip/hip_runtime.h>
#include <hip/hip_bf16.h>
#include <math.h>

#define B_  8
#define S_  512
#define H_  768
#define NH_ 12
#define D_  64
#define I_  3072
#define NTOK (B_*S_)   // 4096
#define LDQ 2304       // fused qkv row stride

typedef __attribute__((ext_vector_type(8))) __bf16 bf16x8;
typedef __attribute__((ext_vector_type(8))) unsigned short ushort8;
typedef __attribute__((ext_vector_type(4))) float  f32x4;

__device__ __forceinline__ float gelu_exact(float x) {
    return 0.5f * x * (1.0f + erff(x * 0.70710678118654752440f));
}

__device__ __forceinline__ unsigned short f2bf(float x) {
    __hip_bfloat16 h = __float2bfloat16(x);
    return *reinterpret_cast<unsigned short*>(&h);
}

__device__ __forceinline__ void gload16(const void* g, void* l) {
    __builtin_amdgcn_global_load_lds(
        (const __attribute__((address_space(1))) void*)g,
        (__attribute__((address_space(3))) void*)l,
        16, 0, 0);
}

// -------------------- f32 [K][N] -> bf16 [N][K] transpose-convert --------------------
__global__ void cvtT_kernel(const float* __restrict__ W, __hip_bfloat16* __restrict__ WT,
                            int K, int N) {
    __shared__ float tile[32][33];
    int k0 = blockIdx.y * 32, n0 = blockIdx.x * 32;
    int tx = threadIdx.x & 31, ty = threadIdx.x >> 5;   // 32x8
    #pragma unroll
    for (int i = 0; i < 32; i += 8)
        tile[ty + i][tx] = W[(long)(k0 + ty + i) * N + n0 + tx];
    __syncthreads();
    #pragma unroll
    for (int i = 0; i < 32; i += 8)
        WT[(long)(n0 + ty + i) * K + k0 + tx] = __float2bfloat16(tile[tx][ty + i]);
}

// -------------------- embeddings + LayerNorm (f32 + bf16 outputs) --------------------
__global__ void embed_ln_kernel(const int* __restrict__ ids,
                                const float* __restrict__ Wword,
                                const float* __restrict__ Wpos,
                                const float* __restrict__ Wtype,
                                const float* __restrict__ g,
                                const float* __restrict__ b,
                                float* __restrict__ out,
                                __hip_bfloat16* __restrict__ outb) {
    int t = blockIdx.x;
    int s = t % S_;
    long id = ids[t];
    int tid = threadIdx.x;
    float vals[3];
    float sum = 0.f, sq = 0.f;
    #pragma unroll
    for (int i = 0; i < 3; ++i) {
        int c = tid + 256 * i;
        float e = Wword[id * H_ + c] + Wpos[(long)s * H_ + c] + Wtype[c];
        vals[i] = e; sum += e; sq += e * e;
    }
    __shared__ float r1[256], r2[256];
    r1[tid] = sum; r2[tid] = sq; __syncthreads();
    for (int st = 128; st > 0; st >>= 1) {
        if (tid < st) { r1[tid] += r1[tid + st]; r2[tid] += r2[tid + st]; }
        __syncthreads();
    }
    float mean = r1[0] * (1.0f / H_);
    float var  = r2[0] * (1.0f / H_) - mean * mean;
    float inv  = rsqrtf(var + 1e-12f);
    #pragma unroll
    for (int i = 0; i < 3; ++i) {
        int c = tid + 256 * i;
        float v = (vals[i] - mean) * inv * g[c] + b[c];
        out[(long)t * H_ + c] = v;
        outb[(long)t * H_ + c] = __float2bfloat16(v);
    }
}

// -------------------- LN(a + r) (f32 + bf16 outputs) --------------------
__global__ void add_ln_kernel(const float* __restrict__ a,
                              const float* __restrict__ r,
                              const float* __restrict__ g,
                              const float* __restrict__ bb,
                              float* __restrict__ out,
                              __hip_bfloat16* __restrict__ outb) {
    int t = blockIdx.x;
    int tid = threadIdx.x;
    float vals[3];
    float sum = 0.f, sq = 0.f;
    #pragma unroll
    for (int i = 0; i < 3; ++i) {
        int c = tid + 256 * i;
        float e = a[(long)t * H_ + c] + r[(long)t * H_ + c];
        vals[i] = e; sum += e; sq += e * e;
    }
    __shared__ float r1[256], r2[256];
    r1[tid] = sum; r2[tid] = sq; __syncthreads();
    for (int st = 128; st > 0; st >>= 1) {
        if (tid < st) { r1[tid] += r1[tid + st]; r2[tid] += r2[tid + st]; }
        __syncthreads();
    }
    float mean = r1[0] * (1.0f / H_);
    float var  = r2[0] * (1.0f / H_) - mean * mean;
    float inv  = rsqrtf(var + 1e-12f);
    #pragma unroll
    for (int i = 0; i < 3; ++i) {
        int c = tid + 256 * i;
        float v = (vals[i] - mean) * inv * g[c] + bb[c];
        out[(long)t * H_ + c] = v;
        outb[(long)t * H_ + c] = __float2bfloat16(v);
    }
}

// -------------------- bf16 MFMA GEMM (m97 structure, tiled BMxBN) --------------------
// BM = 16*MI*WR, BN = 16*NJ*WC, WR*WC = 4 waves.
template<int BM, int BN, int MI, int NJ, int ACT, int WF32, int WB16>
__global__ __launch_bounds__(256, 2) void mfma_gemm_kernel(
    const __hip_bfloat16* __restrict__ A,
    const __hip_bfloat16* __restrict__ BT,
    const float* __restrict__ bias,
    float* __restrict__ Cf,
    __hip_bfloat16* __restrict__ Cb,
    int M, int N, int K) {
    constexpr int WC = BN / (NJ * 16);
    constexpr int WR = BM / (MI * 16);
    static_assert(WR * WC == 4, "4 waves");
    __shared__ __align__(16) __hip_bfloat16 sA[BM * 32];
    __shared__ __align__(16) __hip_bfloat16 sB[BN * 32];
    const int tid  = threadIdx.x;
    const int lane = tid & 63;
    const int w    = tid >> 6;
    const int wr   = w / WC, wc = w % WC;
    const int l15  = lane & 15, l4 = lane >> 4;
    const int m0 = blockIdx.y * BM, n0 = blockIdx.x * BN;

    f32x4 acc[MI][NJ] = {};

    for (int k0 = 0; k0 < K; k0 += 32) {
        #pragma unroll
        for (int t = 0; t < BM * 4 / 256; ++t) {
            int c = tid + 256 * t;
            gload16(A + (long)(m0 + (c >> 2)) * K + k0 + (c & 3) * 8, sA + c * 8);
        }
        #pragma unroll
        for (int t = 0; t < BN * 4 / 256; ++t) {
            int c = tid + 256 * t;
            gload16(BT + (long)(n0 + (c >> 2)) * K + k0 + (c & 3) * 8, sB + c * 8);
        }
        __syncthreads();
        const int kk = l4 * 8;
        bf16x8 af[MI], bf[NJ];
        #pragma unroll
        for (int i = 0; i < MI; ++i)
            af[i] = *reinterpret_cast<const bf16x8*>(sA + (wr * MI * 16 + i * 16 + l15) * 32 + kk);
        #pragma unroll
        for (int j = 0; j < NJ; ++j)
            bf[j] = *reinterpret_cast<const bf16x8*>(sB + (wc * NJ * 16 + j * 16 + l15) * 32 + kk);
        #pragma unroll
        for (int i = 0; i < MI; ++i)
            #pragma unroll
            for (int j = 0; j < NJ; ++j)
                acc[i][j] = __builtin_amdgcn_mfma_f32_16x16x32_bf16(af[i], bf[j], acc[i][j], 0, 0, 0);
        __syncthreads();
    }

    #pragma unroll
    for (int i = 0; i < MI; ++i) {
        #pragma unroll
        for (int j = 0; j < NJ; ++j) {
            int col = n0 + wc * NJ * 16 + j * 16 + l15;
            float bv = bias[col];
            #pragma unroll
            for (int r = 0; r < 4; ++r) {
                int row = m0 + wr * MI * 16 + i * 16 + l4 * 4 + r;
                float v = acc[i][j][r] + bv;
                if (ACT == 1) v = gelu_exact(v);
                if (WF32) Cf[(long)row * N + col] = v;
                if (WB16) Cb[(long)row * N + col] = __float2bfloat16(v);
            }
        }
    }
}

// -------------------- fused flash attention on fused QKV buffer --------------------
// grid (S/64, B*NH); block 256 = 4 waves; wave handles 16 q-rows.
__global__ __launch_bounds__(256, 4) void flash_attn_kernel(
    const __hip_bfloat16* __restrict__ QKV,
    __hip_bfloat16* __restrict__ Ctx) {
    __shared__ __align__(16) unsigned short sK[64 * 72];    // K tile [kv][d], pad 8
    __shared__ __align__(16) unsigned short sVt[64 * 72];   // V^T tile [d][kv], pad 8
    __shared__ __align__(16) unsigned short sP[4 * 16 * 72];

    const int tid  = threadIdx.x;
    const int lane = tid & 63;
    const int w    = tid >> 6;
    const int l15  = lane & 15, l4 = lane >> 4;
    const int qb = blockIdx.x;
    const int bh = blockIdx.y;
    const int b  = bh / NH_, hd = bh % NH_;
    const long rbase = (long)b * S_ * LDQ;
    const int qoff = hd * D_, koff = H_ + hd * D_, voff = 2 * H_ + hd * D_;

    const int qrow0 = qb * 64 + w * 16;
    bf16x8 af[2];
    #pragma unroll
    for (int ks = 0; ks < 2; ++ks)
        af[ks] = *reinterpret_cast<const bf16x8*>(
            QKV + rbase + (long)(qrow0 + l15) * LDQ + qoff + ks * 32 + l4 * 8);

    f32x4 ctx[4] = {};
    float m_run[4], l_run[4];
    #pragma unroll
    for (int r = 0; r < 4; ++r) { m_run[r] = -1e30f; l_run[r] = 0.f; }

    const int sr = tid >> 2;
    const int sc = (tid & 3) * 16;
    unsigned short* pl = sP + w * (16 * 72);

    for (int kv0 = 0; kv0 < S_; kv0 += 64) {
        const __hip_bfloat16* kg = QKV + rbase + (long)(kv0 + sr) * LDQ + koff + sc;
        const __hip_bfloat16* vg = QKV + rbase + (long)(kv0 + sr) * LDQ + voff + sc;
        ushort8 kv_a = *reinterpret_cast<const ushort8*>(kg);
        ushort8 kv_b = *reinterpret_cast<const ushort8*>(kg + 8);
        ushort8 vv_a = *reinterpret_cast<const ushort8*>(vg);
        ushort8 vv_b = *reinterpret_cast<const ushort8*>(vg + 8);
        __syncthreads();
        *reinterpret_cast<ushort8*>(sK + sr * 72 + sc)     = kv_a;
        *reinterpret_cast<ushort8*>(sK + sr * 72 + sc + 8) = kv_b;
        #pragma unroll
        for (int i = 0; i < 8; ++i) {
            sVt[(sc + i) * 72 + sr]     = vv_a[i];
            sVt[(sc + 8 + i) * 72 + sr] = vv_b[i];
        }
        __syncthreads();

        f32x4 s[4];
        #pragma unroll
        for (int j = 0; j < 4; ++j) {
            s[j] = (f32x4){0.f, 0.f, 0.f, 0.f};
            #pragma unroll
            for (int ks = 0; ks < 2; ++ks) {
                bf16x8 bk = *reinterpret_cast<const bf16x8*>(sK + (j * 16 + l15) * 72 + ks * 32 + l4 * 8);
                s[j] = __builtin_amdgcn_mfma_f32_16x16x32_bf16(af[ks], bk, s[j], 0, 0, 0);
            }
        }
        #pragma unroll
        for (int j = 0; j < 4; ++j) s[j] *= 0.125f;

        #pragma unroll
        for (int r = 0; r < 4; ++r) {
            float mx = fmaxf(fmaxf(s[0][r], s[1][r]), fmaxf(s[2][r], s[3][r]));
            #pragma unroll
            for (int o = 1; o < 16; o <<= 1) mx = fmaxf(mx, __shfl_xor(mx, o));
            float mnew = fmaxf(m_run[r], mx);
            float sum = 0.f;
            #pragma unroll
            for (int j = 0; j < 4; ++j) {
                float p = __expf(s[j][r] - mnew);
                s[j][r] = p; sum += p;
            }
            #pragma unroll
            for (int o = 1; o < 16; o <<= 1) sum += __shfl_xor(sum, o);
            float resc = __expf(m_run[r] - mnew);
            l_run[r] = l_run[r] * resc + sum;
            m_run[r] = mnew;
            #pragma unroll
            for (int j = 0; j < 4; ++j) ctx[j][r] *= resc;
        }

        #pragma unroll
        for (int j = 0; j < 4; ++j)
            #pragma unroll
            for (int r = 0; r < 4; ++r)
                pl[(l4 * 4 + r) * 72 + j * 16 + l15] = f2bf(s[j][r]);

        #pragma unroll
        for (int ks = 0; ks < 2; ++ks) {
            bf16x8 ap = *reinterpret_cast<const bf16x8*>(pl + l15 * 72 + ks * 32 + l4 * 8);
            #pragma unroll
            for (int jd = 0; jd < 4; ++jd) {
                bf16x8 bv = *reinterpret_cast<const bf16x8*>(sVt + (jd * 16 + l15) * 72 + ks * 32 + l4 * 8);
                ctx[jd] = __builtin_amdgcn_mfma_f32_16x16x32_bf16(ap, bv, ctx[jd], 0, 0, 0);
            }
        }
    }

    #pragma unroll
    for (int r = 0; r < 4; ++r) {
        float inv = 1.f / l_run[r];
        long tok = (long)b * S_ + qb * 64 + w * 16 + l4 * 4 + r;
        #pragma unroll
        for (int jd = 0; jd < 4; ++jd)
            Ctx[tok * H_ + hd * D_ + jd * 16 + l15] = __float2bfloat16(ctx[jd][r] * inv);
    }
}

// -------------------- pooled head: out[b,n] = h[b,0,:] . Wp[:,n] + bp[n] --------------------
// grid (3, 8), block 256: thread handles one output column.
__global__ void pooled_kernel(const float* __restrict__ h,
                              const float* __restrict__ Wp,
                              const float* __restrict__ bp,
                              float* __restrict__ out) {
    int b = blockIdx.y;
    int col = blockIdx.x * 256 + threadIdx.x;
    const float* hb = h + (long)b * S_ * H_;
    float acc = 0.f;
    #pragma unroll 8
    for (int k = 0; k < H_; ++k)
        acc += hb[k] * Wp[(long)k * H_ + col];
    out[(long)b * H_ + col] = acc + bp[col];
}

extern "C" void kernel_launch(void* const* d_in, const int* in_sizes, int n_in,
                              void* d_out, int out_size, void* d_ws, size_t ws_size,
                              hipStream_t stream) {
    const int*   x      = (const int*)  d_in[0];
    const float* W_word = (const float*)d_in[1];
    const float* W_pos  = (const float*)d_in[2];
    const float* W_type = (const float*)d_in[3];
    const float* g_emb  = (const float*)d_in[4];
    const float* b_emb  = (const float*)d_in[5];
    const float* Wq     = (const float*)d_in[6];
    const float* bq     = (const float*)d_in[7];
    const float* Wk     = (const float*)d_in[8];
    const float* bk     = (const float*)d_in[9];
    const float* Wv     = (const float*)d_in[10];
    const float* bv     = (const float*)d_in[11];
    const float* Wo     = (const float*)d_in[12];
    const float* bo     = (const float*)d_in[13];
    const float* g_attn = (const float*)d_in[14];
    const float* b_attn = (const float*)d_in[15];
    const float* Wi     = (const float*)d_in[16];
    const float* bi     = (const float*)d_in[17];
    const float* Wd     = (const float*)d_in[18];
    const float* bd     = (const float*)d_in[19];
    const float* g_out  = (const float*)d_in[20];
    const float* b_out  = (const float*)d_in[21];
    const float* Wp     = (const float*)d_in[22];
    const float* bp     = (const float*)d_in[23];

    const size_t NT = (size_t)NTOK * H_;
    char* base = (char*)d_ws;
    size_t off = 0;
    auto alloc = [&](size_t bytes) -> char* {
        char* p = base + off;
        off += (bytes + 255) & ~(size_t)255;
        return p;
    };
    float* h    = (float*)alloc(NT * 4);
    float* xa   = (float*)alloc(NT * 4);
    float* kb   = (float*)alloc(NT * 4);   // O-proj / FF2 f32 out
    __hip_bfloat16* h_b   = (__hip_bfloat16*)alloc(NT * 2);
    __hip_bfloat16* xa_b  = (__hip_bfloat16*)alloc(NT * 2);
    __hip_bfloat16* qkv_b = (__hip_bfloat16*)alloc((size_t)NTOK * LDQ * 2);
    __hip_bfloat16* ctx_b = (__hip_bfloat16*)alloc(NT * 2);
    __hip_bfloat16* ff1_b = (__hip_bfloat16*)alloc((size_t)NTOK * I_ * 2);
    __hip_bfloat16* WqkvT = (__hip_bfloat16*)alloc((size_t)LDQ * H_ * 2);
    __hip_bfloat16* WoT = (__hip_bfloat16*)alloc((size_t)H_ * H_ * 2);
    __hip_bfloat16* WiT = (__hip_bfloat16*)alloc((size_t)H_ * I_ * 2);
    __hip_bfloat16* WdT = (__hip_bfloat16*)alloc((size_t)I_ * H_ * 2);
    float* bqkv = (float*)alloc(LDQ * 4);

    // fused QKV weight (transposed) + bias
    cvtT_kernel<<<dim3(H_/32, H_/32), 256, 0, stream>>>(Wq, WqkvT, H_, H_);
    cvtT_kernel<<<dim3(H_/32, H_/32), 256, 0, stream>>>(Wk, WqkvT + (size_t)H_ * H_, H_, H_);
    cvtT_kernel<<<dim3(H_/32, H_/32), 256, 0, stream>>>(Wv, WqkvT + (size_t)2 * H_ * H_, H_, H_);
    cvtT_kernel<<<dim3(H_/32, H_/32), 256, 0, stream>>>(Wo, WoT, H_, H_);
    cvtT_kernel<<<dim3(I_/32, H_/32), 256, 0, stream>>>(Wi, WiT, H_, I_);
    cvtT_kernel<<<dim3(H_/32, I_/32), 256, 0, stream>>>(Wd, WdT, I_, H_);
    hipMemcpyAsync(bqkv,          bq, H_ * 4, hipMemcpyDeviceToDevice, stream);
    hipMemcpyAsync(bqkv + H_,     bk, H_ * 4, hipMemcpyDeviceToDevice, stream);
    hipMemcpyAsync(bqkv + 2 * H_, bv, H_ * 4, hipMemcpyDeviceToDevice, stream);

    embed_ln_kernel<<<NTOK, 256, 0, stream>>>(x, W_word, W_pos, W_type, g_emb, b_emb, h, h_b);

    dim3 gqkv(LDQ/128, NTOK/128);  // (18, 32)
    dim3 g768(H_/64,  NTOK/128);   // (12, 32) — 128x64 tiles
    dim3 gi(I_/128,  NTOK/128);    // (24, 32)
    for (int layer = 0; layer < 6; ++layer) {
        mfma_gemm_kernel<128,128,4,4,0,0,1><<<gqkv, 256, 0, stream>>>(
            h_b, WqkvT, bqkv, nullptr, qkv_b, NTOK, LDQ, H_);
        flash_attn_kernel<<<dim3(S_/64, B_*NH_), 256, 0, stream>>>(qkv_b, ctx_b);
        mfma_gemm_kernel<128,64,4,2,0,1,0><<<g768, 256, 0, stream>>>(
            ctx_b, WoT, bo, kb, nullptr, NTOK, H_, H_);
        add_ln_kernel<<<NTOK, 256, 0, stream>>>(h, kb, g_attn, b_attn, xa, xa_b);
        mfma_gemm_kernel<128,128,4,4,1,0,1><<<gi, 256, 0, stream>>>(
            xa_b, WiT, bi, nullptr, ff1_b, NTOK, I_, H_);
        mfma_gemm_kernel<128,64,4,2,0,1,0><<<g768, 256, 0, stream>>>(
            ff1_b, WdT, bd, kb, nullptr, NTOK, H_, I_);
        add_ln_kernel<<<NTOK, 256, 0, stream>>>(xa, kb, g_out, b_out, h, h_b);
    }

    hipMemcpyAsync(d_out, h, NT * sizeof(float), hipMemcpyDeviceToDevice, stream);
    pooled_kernel<<<dim3(3, 8), 256, 0, stream>>>(h, Wp, bp, (float*)d_out + NT);
}